// Round 1
// 820.054 us; speedup vs baseline: 1.0360x; 1.0360x over previous
//
#include <hip/hip_runtime.h>
#include <hip/hip_bf16.h>
#include <stdint.h>

// ---------------- problem constants ----------------
#define LL      3
#define NNODES  4000
#define NRELS   200
#define VV      20
#define EMB     128
#define HIDD    128
#define OUTD    100
#define WS_N    50000
#define WS_E    800000
#define BV      32
#define DECAYF  0.03f
#define AK      4032   // K padded to multiple of 64 for BK=64 glds staging
#define ZSTRIDE ((long)LL*640*4000)   // one split-K partial of z (bf16)
#define SCAN_NB 196    // ceil(WS_N/256)
#define NPP     391    // (WS_N+127)/128 pool-partial blocks

typedef __bf16 bf16x8 __attribute__((ext_vector_type(8)));
typedef __bf16 bf16x4 __attribute__((ext_vector_type(4)));
typedef __bf16 bf16x2 __attribute__((ext_vector_type(2)));
typedef float  f32x4  __attribute__((ext_vector_type(4)));

// async global->LDS, 16B per lane; LDS dest = wave-uniform base + lane*16 (m97/m104)
__device__ __forceinline__ void glds16(const __bf16* g, __bf16* l) {
    __builtin_amdgcn_global_load_lds((const __attribute__((address_space(1))) void*)g,
                                     (__attribute__((address_space(3))) void*)l, 16, 0, 0);
}

// ---------------- f32 -> bf16 conversion, zero-padded K tail; visit + alpha + beta fused (R8) ----------------
__global__ __launch_bounds__(256) void k_cvt2(const float* __restrict__ visit,
                                              const float* __restrict__ alpha_w,
                                              const float* __restrict__ beta_w,
                                              const float* __restrict__ beta_b,
                                              __bf16* __restrict__ visit_bf,
                                              __bf16* __restrict__ alpha_bf,
                                              float* __restrict__ betab) {
    long bid = blockIdx.x;
    const bool isv = bid < BV*VV;          // block-uniform
    const float* ip; __bf16* op;
    if (isv) { ip = visit + bid*4000; op = visit_bf + bid*AK; }
    else     { long r = bid - BV*VV; ip = alpha_w + r*4000; op = alpha_bf + r*AK; }
    int t = threadIdx.x;
    float p0 = 0.f, p1 = 0.f, p2 = 0.f;
    if (t < 250) {
        const float4* p4 = (const float4*)ip + t*4;
        float4 f0 = p4[0], f1 = p4[1], f2 = p4[2], f3 = p4[3];
        bf16x8 h0, h1;
        h0[0]=(__bf16)f0.x; h0[1]=(__bf16)f0.y; h0[2]=(__bf16)f0.z; h0[3]=(__bf16)f0.w;
        h0[4]=(__bf16)f1.x; h0[5]=(__bf16)f1.y; h0[6]=(__bf16)f1.z; h0[7]=(__bf16)f1.w;
        h1[0]=(__bf16)f2.x; h1[1]=(__bf16)f2.y; h1[2]=(__bf16)f2.z; h1[3]=(__bf16)f2.w;
        h1[4]=(__bf16)f3.x; h1[5]=(__bf16)f3.y; h1[6]=(__bf16)f3.z; h1[7]=(__bf16)f3.w;
        ((bf16x8*)op)[t*2]   = h0;
        ((bf16x8*)op)[t*2+1] = h1;
        if (isv) {
            // beta partials for the 3 layers (fused from old k_beta: same visit row)
            #pragma unroll
            for (int l = 0; l < LL; l++) {
                const float4* bw = (const float4*)(beta_w + (long)l*4000) + t*4;
                float4 b0 = bw[0], b1 = bw[1], b2 = bw[2], b3 = bw[3];
                float s = f0.x*b0.x + f0.y*b0.y + f0.z*b0.z + f0.w*b0.w
                        + f1.x*b1.x + f1.y*b1.y + f1.z*b1.z + f1.w*b1.w
                        + f2.x*b2.x + f2.y*b2.y + f2.z*b2.z + f2.w*b2.w
                        + f3.x*b3.x + f3.y*b3.y + f3.z*b3.z + f3.w*b3.w;
                if (l == 0) p0 = s; else if (l == 1) p1 = s; else p2 = s;
            }
        }
    } else if (t < 254) {
        bf16x8 zz;
        #pragma unroll
        for (int j = 0; j < 8; j++) zz[j] = (__bf16)0.f;
        ((bf16x8*)op)[500 + (t - 250)] = zz;
    }
    if (isv) {
        __shared__ float r0[256], r1[256], r2[256];
        r0[t] = p0; r1[t] = p1; r2[t] = p2;
        __syncthreads();
        for (int o = 128; o > 0; o >>= 1) {
            if (t < o) { r0[t] += r0[t+o]; r1[t] += r1[t+o]; r2[t] += r2[t+o]; }
            __syncthreads();
        }
        if (t == 0) {
            int v = (int)(bid % VV);
            float lam = __expf(DECAYF * (float)(VV - v));
            betab[0*BV*VV + bid] = tanhf(r0[0] + beta_b[0]) * lam;
            betab[1*BV*VV + bid] = tanhf(r1[0] + beta_b[1]) * lam;
            betab[2*BV*VV + bid] = tanhf(r2[0] + beta_b[2]) * lam;
        }
    }
}

// ---------------- alpha GEMM: z[l,row,col] = visit[row,:] . alpha_w[l][col,:] ----------------
// bf16 in (stride AK), BK=64 glds16 staging, XOR-swizzled LDS (0 bank conflicts, R5),
// XCD-grouped swizzle (R3), split-K=4 with bf16 partial stores (R6).
__global__ __launch_bounds__(256)
void gemm_alpha(const __bf16* __restrict__ visit_bf, const __bf16* __restrict__ alpha_bf,
                __bf16* __restrict__ zpart)
{
    __shared__ __bf16 Ah[128*64];   // granule g of row r at r*64 + (g^(r&7))*8
    __shared__ __bf16 Bh[128*64];

    const int id   = blockIdx.x;      // 0..1919
    const int xcd  = id & 7;
    const int slot = id >> 3;         // 0..239
    const int mi   = slot % 5;        // 0..4
    const int gix  = slot / 5;        // 0..47
    const int g    = xcd * 48 + gix;  // 0..383
    const int ni   = g & 31;          // 0..31
    const int lkh  = g >> 5;          // 0..11
    const int l    = lkh >> 2;        // 0..2
    const int kh   = lkh & 3;         // 0..3

    const __bf16* Ag = visit_bf;
    const __bf16* Bg = alpha_bf + (long)l * NNODES * AK;
    __bf16*       Cg = zpart + (long)kh * ZSTRIDE + (long)l * 640 * 4000;
    const int m0 = mi * 128;
    const int n0 = ni * 128;
    const int k0 = kh * 1024;
    const int k1 = (kh == 3) ? AK : (k0 + 1024);

    const int tid = threadIdx.x;
    const int wv  = tid >> 6;
    const int ln  = tid & 63;
    const int srow = ln >> 3;
    const int gsl  = (ln & 7) ^ srow;

    const __bf16* aA = Ag + (long)(m0 + wv*8 + srow) * AK + gsl*8;
    const __bf16* bB[4];
    #pragma unroll
    for (int t = 0; t < 4; t++) {
        int br = n0 + wv*8 + srow + t*32;
        if (br > NNODES-1) br = NNODES-1;      // clamp (cols>=4000 masked at store)
        bB[t] = Bg + (long)br * AK + gsl*8;
    }

    const int wm = (wv & 1) * 64;
    const int wn = (wv >> 1) * 64;
    const int lr = ln & 15;
    const int kq = ln >> 4;
    const int sw0 = lr & 7;

    f32x4 acc[4][4];
    #pragma unroll
    for (int i = 0; i < 4; i++)
        #pragma unroll
        for (int j = 0; j < 4; j++)
            acc[i][j] = (f32x4){0.f, 0.f, 0.f, 0.f};

    for (int kb = k0; kb < k1; kb += 64) {
        #pragma unroll
        for (int t = 0; t < 4; t++) {
            glds16(aA + (long)t*32*AK + kb, &Ah[(t*4 + wv) * 512]);
            glds16(bB[t] + kb,              &Bh[(t*4 + wv) * 512]);
        }
        __syncthreads();
        #pragma unroll
        for (int ks = 0; ks < 2; ks++) {
            const int sg = ((ks*4 + kq) ^ sw0) * 8;
            bf16x8 af[4], bfr[4];
            #pragma unroll
            for (int i = 0; i < 4; i++) {
                af[i]  = *(const bf16x8*)&Ah[(wm + i*16 + lr)*64 + sg];
                bfr[i] = *(const bf16x8*)&Bh[(wn + i*16 + lr)*64 + sg];
            }
            #pragma unroll
            for (int i = 0; i < 4; i++)
                #pragma unroll
                for (int j = 0; j < 4; j++)
                    acc[i][j] = __builtin_amdgcn_mfma_f32_16x16x32_bf16(af[i], bfr[j], acc[i][j], 0, 0, 0);
        }
        __syncthreads();
    }

    // C/D layout col=lane&15, row=(lane>>4)*4+reg (m89/m91-verified)
    #pragma unroll
    for (int i = 0; i < 4; i++) {
        const int row_b = m0 + wm + i*16 + kq*4;   // < 640 always
        #pragma unroll
        for (int j = 0; j < 4; j++) {
            const int col = n0 + wn + j*16 + lr;
            if (col < NNODES) {
                #pragma unroll
                for (int r = 0; r < 4; r++)
                    Cg[(long)(row_b + r)*4000 + col] = (__bf16)acc[i][j][r];
            }
        }
    }
}

// ---------------- generic small GEMM (C = A * B^T), split-bf16 for ~f32 accuracy ----------------
#define BM 128
#define BN 128
#define BKG 32
#define LSTR 40

template<int SPLIT>
__device__ __forceinline__ void stage_tile(const float* __restrict__ G, int rows, int Kdim,
                                           int r0, int kb, int k1, __bf16* Sh, __bf16* Sl, int tid)
{
    const int sr  = tid >> 1;
    const int skc = (tid & 1) * 16;
    const int gr  = r0 + sr;
    const int gk  = kb + skc;
    float va[16];
    if (gr < rows && gk + 16 <= k1) {
        const float4* p4 = (const float4*)(G + (long)gr * Kdim + gk);
        #pragma unroll
        for (int q = 0; q < 4; q++) {
            float4 f = p4[q];
            va[4*q+0] = f.x; va[4*q+1] = f.y; va[4*q+2] = f.z; va[4*q+3] = f.w;
        }
    } else {
        #pragma unroll
        for (int j = 0; j < 16; j++) {
            int kk = gk + j;
            va[j] = (gr < rows && kk < k1) ? G[(long)gr * Kdim + kk] : 0.0f;
        }
    }
    bf16x8 h[2], lo[2];
    #pragma unroll
    for (int half = 0; half < 2; half++) {
        #pragma unroll
        for (int j = 0; j < 8; j++) {
            float v = va[half*8 + j];
            __bf16 hi = (__bf16)v;
            h[half][j]  = hi;
            lo[half][j] = (__bf16)(v - (float)hi);
        }
    }
    *(bf16x8*)&Sh[sr*LSTR + skc]     = h[0];
    *(bf16x8*)&Sh[sr*LSTR + skc + 8] = h[1];
    if (SPLIT) {
        *(bf16x8*)&Sl[sr*LSTR + skc]     = lo[0];
        *(bf16x8*)&Sl[sr*LSTR + skc + 8] = lo[1];
    }
}

template<int SPLIT, int RELU, int BIAS, int WRITEB>
__global__ __launch_bounds__(256)
void gemm_bt(const float* __restrict__ Ag, const float* __restrict__ Bg,
             float* __restrict__ Cg, const float* __restrict__ bias,
             __bf16* __restrict__ Xb, int M, int N, int K)
{
    __shared__ __bf16 Ah[BM*LSTR];
    __shared__ __bf16 Bh[BN*LSTR];
    __shared__ __bf16 Alo[SPLIT ? BM*LSTR : 1];
    __shared__ __bf16 Blo[SPLIT ? BN*LSTR : 1];

    const int tid = threadIdx.x;
    const int m0 = blockIdx.x * BM;
    const int n0 = blockIdx.y * BN;

    const int wave = tid >> 6;
    const int lane = tid & 63;
    const int wm = (wave & 1) * 64;
    const int wn = (wave >> 1) * 64;
    const int lr = lane & 15;
    const int kq = lane >> 4;

    f32x4 acc[4][4];
    #pragma unroll
    for (int i = 0; i < 4; i++)
        #pragma unroll
        for (int j = 0; j < 4; j++)
            acc[i][j] = (f32x4){0.f, 0.f, 0.f, 0.f};

    for (int kb = 0; kb < K; kb += BKG) {
        stage_tile<SPLIT>(Ag, M, K, m0, kb, K, Ah, Alo, tid);
        stage_tile<SPLIT>(Bg, N, K, n0, kb, K, Bh, Blo, tid);
        __syncthreads();

        bf16x8 af[4], bfr[4];
        #pragma unroll
        for (int i = 0; i < 4; i++) {
            af[i]  = *(const bf16x8*)&Ah[(wm + i*16 + lr)*LSTR + kq*8];
            bfr[i] = *(const bf16x8*)&Bh[(wn + i*16 + lr)*LSTR + kq*8];
        }
        #pragma unroll
        for (int i = 0; i < 4; i++)
            #pragma unroll
            for (int j = 0; j < 4; j++)
                acc[i][j] = __builtin_amdgcn_mfma_f32_16x16x32_bf16(af[i], bfr[j], acc[i][j], 0, 0, 0);

        if (SPLIT) {
            bf16x8 al[4], bl[4];
            #pragma unroll
            for (int i = 0; i < 4; i++) {
                al[i] = *(const bf16x8*)&Alo[(wm + i*16 + lr)*LSTR + kq*8];
                bl[i] = *(const bf16x8*)&Blo[(wn + i*16 + lr)*LSTR + kq*8];
            }
            #pragma unroll
            for (int i = 0; i < 4; i++)
                #pragma unroll
                for (int j = 0; j < 4; j++) {
                    acc[i][j] = __builtin_amdgcn_mfma_f32_16x16x32_bf16(af[i], bl[j], acc[i][j], 0, 0, 0);
                    acc[i][j] = __builtin_amdgcn_mfma_f32_16x16x32_bf16(al[i], bfr[j], acc[i][j], 0, 0, 0);
                }
        }
        __syncthreads();
    }

    #pragma unroll
    for (int i = 0; i < 4; i++) {
        const int row_b = m0 + wm + i*16 + kq*4;
        #pragma unroll
        for (int j = 0; j < 4; j++) {
            const int col = n0 + wn + j*16 + lr;
            if (col < N) {
                #pragma unroll
                for (int r = 0; r < 4; r++) {
                    const int row = row_b + r;
                    if (row < M) {
                        float v = acc[i][j][r];
                        if (BIAS) v += bias[col];
                        if (RELU) v = fmaxf(v, 0.0f);
                        Cg[(long)row*N + col] = v;
                        if (WRITEB) Xb[(long)row*N + col] = (__bf16)v;
                    }
                }
            }
        }
    }
}

// ---------------- CSR build (parallel scan: R7; scan2 fused into scan3: R8) ----------------
__global__ void k_count(const int* __restrict__ dst, int* __restrict__ deg) {
    int e = blockIdx.x*256 + threadIdx.x;
    if (e < WS_E) atomicAdd(&deg[dst[e]], 1);
}

// per-block sum of 256 degrees -> bsum[block]
__global__ __launch_bounds__(256) void k_scan1(const int* __restrict__ deg, int* __restrict__ bsum) {
    __shared__ int red[256];
    int t = threadIdx.x;
    int i = blockIdx.x*256 + t;
    red[t] = (i < WS_N) ? deg[i] : 0;
    __syncthreads();
    for (int o = 128; o > 0; o >>= 1) {
        if (t < o) red[t] += red[t + o];
        __syncthreads();
    }
    if (t == 0) bsum[blockIdx.x] = red[0];
}

// fused: every block redundantly scans the 196 block sums (cheap), then local scan -> offs, cursor
__global__ __launch_bounds__(256) void k_scan3(const int* __restrict__ deg, const int* __restrict__ bsum,
                                               int* __restrict__ offs, int* __restrict__ cursor) {
    __shared__ int sb[256];
    __shared__ int s[256];
    int t = threadIdx.x;
    int bv = (t < SCAN_NB) ? bsum[t] : 0;
    sb[t] = bv;
    __syncthreads();
    for (int o = 1; o < 256; o <<= 1) {
        int add = (t >= o) ? sb[t - o] : 0;
        __syncthreads();
        sb[t] += add;
        __syncthreads();
    }
    int base = (blockIdx.x == 0) ? 0 : sb[blockIdx.x - 1];   // exclusive block base

    int i = blockIdx.x*256 + t;
    int v = (i < WS_N) ? deg[i] : 0;
    s[t] = v;
    __syncthreads();
    for (int o = 1; o < 256; o <<= 1) {
        int add = (t >= o) ? s[t - o] : 0;
        __syncthreads();
        s[t] += add;
        __syncthreads();
    }
    if (i < WS_N) {
        int e = base + s[t] - v;
        offs[i] = e;
        cursor[i] = e;
    }
    if (blockIdx.x == 0 && t == 0) offs[WS_N] = WS_E;
}

__global__ void k_fill(const int* __restrict__ dst, const int* __restrict__ src,
                       const int* __restrict__ rel, int* __restrict__ cursor,
                       int2* __restrict__ sr) {
    int e = blockIdx.x*256 + threadIdx.x;
    if (e < WS_E) {
        int d = dst[e];
        int p = atomicAdd(&cursor[d], 1);
        sr[p] = make_int2(src[e], rel[e]);
    }
}

// ---------------- small precompute kernels ----------------
// fused Wrel GEMM + relmsg (R8): exact f32, kills the split-bf16 Wrel pass + buffer round-trip
__global__ __launch_bounds__(128) void k_relfused(const float* __restrict__ rel_emb,
                                                  const float* __restrict__ lin_w,
                                                  const float* __restrict__ lin_b,
                                                  const float* __restrict__ wr_w,
                                                  const float* __restrict__ wr_b,
                                                  __bf16* __restrict__ relmsg) {
    int r = blockIdx.x;    // 0..NRELS-1
    int o = threadIdx.x;   // 0..127
    __shared__ float row[128];
    __shared__ float red[128];
    row[o] = rel_emb[(long)r*EMB + o];
    __syncthreads();
    float wv = lin_b[o];
    #pragma unroll 4
    for (int k = 0; k < EMB; k++) wv += row[k] * lin_w[(long)o*EMB + k];
    #pragma unroll
    for (int l = 0; l < LL; l++) {
        red[o] = wv * wr_w[l*HIDD + o];
        __syncthreads();
        for (int s2 = 64; s2 > 0; s2 >>= 1) {
            if (o < s2) red[o] += red[o + s2];
            __syncthreads();
        }
        float wrel = red[0] + wr_b[l];
        __syncthreads();   // all lanes read red[0] before next-l overwrite
        relmsg[((long)l*NRELS + r)*HIDD + o] = (__bf16)(wrel * wv);
    }
}

// x init + bf16 shadow + per-layer node attention gather (fused)
__global__ void k_xinit(const float* __restrict__ Wnode, const int* __restrict__ nid,
                        const int* __restrict__ batch, const float* __restrict__ attn,
                        float* __restrict__ x, __bf16* __restrict__ xb, float* __restrict__ an) {
    int t = blockIdx.x*256 + threadIdx.x;
    if (t >= WS_N*32) return;
    int i = t >> 5;
    int d = t & 31;
    int n = nid[i];
    float4 v = ((const float4*)Wnode)[n*32 + d];
    ((float4*)x)[i*32 + d] = v;
    bf16x4 b;
    b[0] = (__bf16)v.x; b[1] = (__bf16)v.y; b[2] = (__bf16)v.z; b[3] = (__bf16)v.w;
    ((bf16x4*)xb)[i*32 + d] = b;
    if (d < LL) an[(long)d*WS_N + i] = attn[((long)d*BV + batch[i]) * NNODES + n];
}

// softmax over v + beta-weighted pool; sums the 4 bf16 split-K partials inline
__global__ __launch_bounds__(256) void k_attnpool(const __bf16* __restrict__ zpart,
                                                  const float* __restrict__ beta, float* __restrict__ attn) {
    int m = blockIdx.x*256 + threadIdx.x;
    int b = blockIdx.y;
    int l = blockIdx.z;
    if (m >= NNODES) return;
    const __bf16* zp = zpart + ((long)l*640 + b*VV) * 4000 + m;
    const float* bet = beta + (l*BV + b) * VV;
    float zv[VV];
    float mx = -1e30f;
    #pragma unroll
    for (int v = 0; v < VV; v++) {
        long o = (long)v * 4000;
        float s = (float)zp[o] + (float)zp[ZSTRIDE + o] + (float)zp[2*ZSTRIDE + o] + (float)zp[3*ZSTRIDE + o];
        zv[v] = s;
        mx = fmaxf(mx, s);
    }
    float s = 0.f, ws = 0.f;
    #pragma unroll
    for (int v = 0; v < VV; v++) {
        float e = __expf(zv[v] - mx);
        s += e;
        ws += e * bet[v];
    }
    attn[((long)l*BV + b) * NNODES + m] = ws / s;
}

// ---------------- message + aggregate ----------------
// R8: 2 edges per wave (lanes 0-31 even edge, 32-63 odd edge), bf16x4 = 8B/lane gathers
// (coalescing sweet spot, halves VMEM instruction count vs 4B/lane), shfl-combine halves.
__global__ __launch_bounds__(256) void k_agg(const float* __restrict__ x, const __bf16* __restrict__ xb,
                                             const float* __restrict__ an,
                                             const __bf16* __restrict__ relmsg_l, const int* __restrict__ offs,
                                             const int2* __restrict__ sr,
                                             float* __restrict__ outb) {
    int node = blockIdx.x*4 + (threadIdx.x >> 6);
    if (node >= WS_N) return;
    int lane = threadIdx.x & 63;
    int half = lane >> 5;     // which edge of the pair
    int lh   = lane & 31;     // dim quad: dims [lh*4, lh*4+4)
    int e0 = offs[node], e1 = offs[node + 1];
    const bf16x4* xb4 = (const bf16x4*)xb;
    const bf16x4* rm4 = (const bf16x4*)relmsg_l;
    float a0 = 0.f, a1 = 0.f, a2 = 0.f, a3 = 0.f;
    int e = e0;
    for (; e + 8 <= e1; e += 8) {
        int2 pe[4];
        #pragma unroll
        for (int q = 0; q < 4; q++) pe[q] = sr[e + 2*q + half];
        float aq[4]; bf16x4 gv[4], mv[4];
        #pragma unroll
        for (int q = 0; q < 4; q++) aq[q] = an[pe[q].x];
        #pragma unroll
        for (int q = 0; q < 4; q++) gv[q] = xb4[pe[q].x*32 + lh];
        #pragma unroll
        for (int q = 0; q < 4; q++) mv[q] = rm4[pe[q].y*32 + lh];
        #pragma unroll
        for (int q = 0; q < 4; q++) {
            a0 += fmaxf((float)gv[q][0]*aq[q] + (float)mv[q][0], 0.f);
            a1 += fmaxf((float)gv[q][1]*aq[q] + (float)mv[q][1], 0.f);
            a2 += fmaxf((float)gv[q][2]*aq[q] + (float)mv[q][2], 0.f);
            a3 += fmaxf((float)gv[q][3]*aq[q] + (float)mv[q][3], 0.f);
        }
    }
    for (; e < e1; e += 2) {
        int ei = e + half;
        bool vld = ei < e1;
        int2 pe = sr[vld ? ei : e];          // safe index for masked lanes
        float aa = vld ? an[pe.x] : 0.f;
        bf16x4 ga = xb4[pe.x*32 + lh];
        bf16x4 va = rm4[pe.y*32 + lh];
        float vm = vld ? 1.f : 0.f;
        a0 += vm * fmaxf((float)ga[0]*aa + (float)va[0], 0.f);
        a1 += vm * fmaxf((float)ga[1]*aa + (float)va[1], 0.f);
        a2 += vm * fmaxf((float)ga[2]*aa + (float)va[2], 0.f);
        a3 += vm * fmaxf((float)ga[3]*aa + (float)va[3], 0.f);
    }
    // combine the two edge-halves: lane i and i+32 hold the same dims
    a0 += __shfl_xor(a0, 32);
    a1 += __shfl_xor(a1, 32);
    a2 += __shfl_xor(a2, 32);
    a3 += __shfl_xor(a3, 32);
    if (half == 0) {
        float4 xo = ((const float4*)x)[node*32 + lh];
        float4 r;
        r.x = a0 + xo.x; r.y = a1 + xo.y; r.z = a2 + xo.z; r.w = a3 + xo.w;
        ((float4*)outb)[node*32 + lh] = r;
    }
}

// ---------------- pooling partials (graph-mean + ehr branch fused: R8) ----------------
__global__ __launch_bounds__(256) void k_pool(const float* __restrict__ x,
                                              const int* __restrict__ batch,
                                              const float* __restrict__ ehr,
                                              const float* __restrict__ node_emb,
                                              float* __restrict__ xgsum,
                                              float* __restrict__ xnsum,
                                              float* __restrict__ esum) {
    if (blockIdx.x < NPP) {
        // graph-sum partials (original k_pool_partial body)
        int r0 = blockIdx.x * 128;
        int d = threadIdx.x & 127;
        int rofs = threadIdx.x >> 7;
        int r1 = min(r0 + 128, WS_N);
        float acc = 0.f;
        int curb = -1;
        for (int i = r0 + rofs; i < r1; i += 2) {
            int b = batch[i];
            if (b != curb) {
                if (curb >= 0) atomicAdd(&xgsum[curb*HIDD + d], acc);
                acc = 0.f; curb = b;
            }
            acc += x[(long)i*HIDD + d];
        }
        if (curb >= 0) atomicAdd(&xgsum[curb*HIDD + d], acc);
    } else {
        // ehr pooling (original k_ehrpool body, adapted to 256 threads)
        int id = blockIdx.x - NPP;     // 0..511
        int b = id >> 4;
        int c = id & 15;
        int d = threadIdx.x;
        int n0 = c * (NNODES/16), n1 = n0 + (NNODES/16);
        __shared__ float red[256];
        if (d < 128) {
            float acc = 0.f;
            for (int n = n0; n < n1; n++)
                acc += ehr[b*NNODES + n] * node_emb[(long)n*HIDD + d];
            atomicAdd(&xnsum[b*HIDD + d], acc);
        }
        float s = 0.f;
        for (int n = n0 + d; n < n1; n += 256) s += ehr[b*NNODES + n];
        red[d] = s; __syncthreads();
        for (int o = 128; o > 0; o >>= 1) {
            if (d < o) red[d] += red[d + o];
            __syncthreads();
        }
        if (d == 0) atomicAdd(&esum[b], red[0]);
    }
}

// fused head: batch-count (binary search) + mean + x_node linear + concat + mlp
__global__ __launch_bounds__(128) void k_head(const float* __restrict__ xgsum,
                                              const float* __restrict__ xnsum,
                                              const float* __restrict__ esum,
                                              const int* __restrict__ batch,
                                              const float* __restrict__ lin_w, const float* __restrict__ lin_b,
                                              const float* __restrict__ mlp_w, const float* __restrict__ mlp_b,
                                              float* __restrict__ out) {
    int b = blockIdx.x;
    int d = threadIdx.x;
    int lo = 0, hi = WS_N;
    while (lo < hi) { int mid = (lo + hi) >> 1; if (batch[mid] < b) lo = mid + 1; else hi = mid; }
    int s0 = lo;
    lo = 0; hi = WS_N;
    while (lo < hi) { int mid = (lo + hi) >> 1; if (batch[mid] < b + 1) lo = mid + 1; else hi = mid; }
    int cnt = max(lo - s0, 1);
    __shared__ float t1[128];
    __shared__ float cat[2*HIDD];
    t1[d]  = xnsum[b*HIDD + d] / esum[b];
    cat[d] = xgsum[b*HIDD + d] / (float)cnt;
    __syncthreads();
    float o2 = lin_b[d];
    for (int k2 = 0; k2 < HIDD; k2++) o2 += t1[k2] * lin_w[d*HIDD + k2];
    cat[HIDD + d] = o2;
    __syncthreads();
    if (d < OUTD) {
        float a = mlp_b[d];
        for (int j = 0; j < 2*HIDD; j++) a += cat[j] * mlp_w[d*2*HIDD + j];
        out[b*OUTD + d] = a;
    }
}

// ---------------- launcher ----------------
extern "C" void kernel_launch(void* const* d_in, const int* in_sizes, int n_in,
                              void* d_out, int out_size, void* d_ws, size_t ws_size,
                              hipStream_t stream)
{
    const float* node_emb = (const float*)d_in[0];
    const float* rel_emb  = (const float*)d_in[1];
    const float* lin_w    = (const float*)d_in[2];
    const float* lin_b    = (const float*)d_in[3];
    const float* alpha_w  = (const float*)d_in[4];
    // d_in[5] alpha_b: shift-invariant under softmax over v -> unused
    const float* beta_w   = (const float*)d_in[6];
    const float* beta_b   = (const float*)d_in[7];
    const float* wr_w     = (const float*)d_in[8];
    const float* wr_b     = (const float*)d_in[9];
    const float* conv_w   = (const float*)d_in[10];
    const float* conv_b   = (const float*)d_in[11];
    const float* mlp_w    = (const float*)d_in[12];
    const float* mlp_b    = (const float*)d_in[13];
    const float* visit    = (const float*)d_in[14];
    const float* ehr      = (const float*)d_in[15];
    const int* node_ids   = (const int*)d_in[16];
    const int* rel_ids    = (const int*)d_in[17];
    const int* ei         = (const int*)d_in[18];
    const int* batch      = (const int*)d_in[19];
    const int* esrc = ei;
    const int* edst = ei + WS_E;
    float* out = (float*)d_out;

    char* p = (char*)d_ws;
    auto take = [&](size_t bytes) -> char* {
        char* q = p;
        p += (bytes + 255) & ~(size_t)255;
        return q;
    };
    __bf16* zpart    = (__bf16*)take((size_t)4*ZSTRIDE*2);        // 61.4 MB: 4 bf16 split-K partials (aggbuf later)
    __bf16* visit_bf = (__bf16*)take((size_t)(BV*VV)*AK*2);       // 5.2 MB
    char*   big      = take((size_t)LL*NNODES*AK*2);              // 96.8 MB: alpha_bf, then carved
    float* betab  = (float*)take((size_t)LL*BV*VV*4);
    // zeroed region: xgsum..deg contiguous -> single memset (R8)
    float* xgsum  = (float*)take((size_t)BV*HIDD*4);
    float* xnsum  = (float*)take((size_t)BV*HIDD*4);
    float* esum   = (float*)take((size_t)BV*4);
    int* deg      = (int*)take((size_t)WS_N*4);
    size_t zero_bytes = (size_t)((char*)(deg + WS_N) - (char*)xgsum);
    int* offs     = (int*)take((size_t)(WS_N+1)*4);
    int* cursor   = (int*)take((size_t)WS_N*4);
    int* bsum     = (int*)take((size_t)SCAN_NB*4);
    if ((size_t)(p - (char*)d_ws) > ws_size) return;  // ws too small: leave output poisoned (visible failure)

    // alpha_bf occupies `big` during cvt+gemm_alpha; afterwards carved (stream-ordered -> safe):
    __bf16* alpha_bf = (__bf16*)big;
    char* q = big;
    auto carve = [&](size_t bytes) -> char* {
        char* r = q;
        q += (bytes + 255) & ~(size_t)255;
        return r;
    };
    float*  x      = (float*)carve((size_t)WS_N*HIDD*4);     // 25.6 MB
    __bf16* xb     = (__bf16*)carve((size_t)WS_N*HIDD*2);    // 12.8 MB
    int2*   sr     = (int2*)carve((size_t)WS_E*8);           // 6.4 MB
    float*  attn   = (float*)carve((size_t)LL*BV*NNODES*4);  // 1.5 MB (written by attnpool AFTER gemm_alpha)
    float*  attnnd = (float*)carve((size_t)LL*WS_N*4);       // 0.6 MB
    float*  Wnode  = (float*)carve((size_t)NNODES*HIDD*4);   // 2.0 MB
    __bf16* relmsg = (__bf16*)carve((size_t)LL*NRELS*HIDD*2);
    float*  aggbuf = (float*)zpart;                          // zpart dead after attnpool

    (void)hipMemsetAsync(xgsum, 0, zero_bytes, stream);

    // ---- phase 1: alpha attention (beta fused into cvt2: R8) ----
    k_cvt2<<<dim3(BV*VV + LL*NNODES), 256, 0, stream>>>(visit, alpha_w, beta_w, beta_b,
                                                        visit_bf, alpha_bf, betab);
    gemm_alpha<<<dim3(1920), 256, 0, stream>>>(visit_bf, alpha_bf, zpart);
    k_attnpool<<<dim3((NNODES+255)/256, BV, LL), 256, 0, stream>>>(zpart, betab, attn);

    // ---- phase 2: graph features (carved from the now-dead alpha_bf region) ----
    k_count<<<dim3((WS_E+255)/256), 256, 0, stream>>>(edst, deg);
    k_scan1<<<dim3(SCAN_NB), 256, 0, stream>>>(deg, bsum);
    k_scan3<<<dim3(SCAN_NB), 256, 0, stream>>>(deg, bsum, offs, cursor);
    k_fill<<<dim3((WS_E+255)/256), 256, 0, stream>>>(edst, esrc, rel_ids, cursor, sr);

    gemm_bt<1,0,1,0><<<dim3((NNODES+BM-1)/BM, 1, 1), 256, 0, stream>>>(
        node_emb, lin_w, Wnode, lin_b, nullptr, NNODES, HIDD, HIDD);
    k_relfused<<<dim3(NRELS), 128, 0, stream>>>(rel_emb, lin_w, lin_b, wr_w, wr_b, relmsg);
    k_xinit<<<dim3((WS_N*32+255)/256), 256, 0, stream>>>(Wnode, node_ids, batch, attn, x, xb, attnnd);

    // ---- phase 3: GNN layers ----
    for (int l = 0; l < LL; l++) {
        k_agg<<<dim3((WS_N+3)/4), 256, 0, stream>>>(
            x, xb, attnnd + (size_t)l*WS_N, relmsg + (size_t)l*NRELS*HIDD, offs, sr, aggbuf);
        gemm_bt<1,1,1,1><<<dim3((WS_N+BM-1)/BM, 1, 1), 256, 0, stream>>>(
            aggbuf, conv_w + (size_t)l*HIDD*HIDD, x, conv_b + (size_t)l*HIDD, xb,
            WS_N, HIDD, HIDD);
    }

    // ---- phase 4: pooling + head ----
    k_pool<<<dim3(NPP + 16*BV), 256, 0, stream>>>(x, batch, ehr, node_emb, xgsum, xnsum, esum);
    k_head<<<BV, 128, 0, stream>>>(xgsum, xnsum, esum, batch, lin_w, lin_b, mlp_w, mlp_b, out);
}

// Round 2
// 771.474 us; speedup vs baseline: 1.1013x; 1.0630x over previous
//
#include <hip/hip_runtime.h>
#include <hip/hip_bf16.h>
#include <stdint.h>

// ---------------- problem constants ----------------
#define LL      3
#define NNODES  4000
#define NRELS   200
#define VV      20
#define EMB     128
#define HIDD    128
#define OUTD    100
#define WS_N    50000
#define WS_E    800000
#define BV      32
#define DECAYF  0.03f
#define AK      4032   // K padded to multiple of 64 for BK=64 glds staging
#define ZSTRIDE ((long)LL*640*4000)   // one split-K partial of z (bf16)
#define SCAN_NB 196    // ceil(WS_N/256)
#define NPP     391    // (WS_N+127)/128 pool-partial blocks
#define CVT_NB  (BV*VV + LL*NNODES)   // cvt blocks before the fused count range
#define CNT_NB  ((WS_E+255)/256)

typedef __bf16 bf16x8 __attribute__((ext_vector_type(8)));
typedef __bf16 bf16x4 __attribute__((ext_vector_type(4)));
typedef __bf16 bf16x2 __attribute__((ext_vector_type(2)));
typedef float  f32x4  __attribute__((ext_vector_type(4)));

// async global->LDS, 16B per lane; LDS dest = wave-uniform base + lane*16 (m97/m104)
__device__ __forceinline__ void glds16(const __bf16* g, __bf16* l) {
    __builtin_amdgcn_global_load_lds((const __attribute__((address_space(1))) void*)g,
                                     (__attribute__((address_space(3))) void*)l, 16, 0, 0);
}

// ---------------- f32 -> bf16 conversion, zero-padded K tail; visit + alpha + beta + edge-count fused ----------------
__global__ __launch_bounds__(256) void k_cvt2(const float* __restrict__ visit,
                                              const float* __restrict__ alpha_w,
                                              const float* __restrict__ beta_w,
                                              const float* __restrict__ beta_b,
                                              __bf16* __restrict__ visit_bf,
                                              __bf16* __restrict__ alpha_bf,
                                              float* __restrict__ betab,
                                              const int* __restrict__ edst,
                                              int* __restrict__ deg) {
    long bid = blockIdx.x;
    int t = threadIdx.x;
    if (bid >= CVT_NB) {
        // fused k_count (R9): independent of the cvt work, saves one dispatch
        int e = (int)(bid - CVT_NB)*256 + t;
        if (e < WS_E) atomicAdd(&deg[edst[e]], 1);
        return;
    }
    const bool isv = bid < BV*VV;          // block-uniform
    const float* ip; __bf16* op;
    if (isv) { ip = visit + bid*4000; op = visit_bf + bid*AK; }
    else     { long r = bid - BV*VV; ip = alpha_w + r*4000; op = alpha_bf + r*AK; }
    float p0 = 0.f, p1 = 0.f, p2 = 0.f;
    if (t < 250) {
        const float4* p4 = (const float4*)ip + t*4;
        float4 f0 = p4[0], f1 = p4[1], f2 = p4[2], f3 = p4[3];
        bf16x8 h0, h1;
        h0[0]=(__bf16)f0.x; h0[1]=(__bf16)f0.y; h0[2]=(__bf16)f0.z; h0[3]=(__bf16)f0.w;
        h0[4]=(__bf16)f1.x; h0[5]=(__bf16)f1.y; h0[6]=(__bf16)f1.z; h0[7]=(__bf16)f1.w;
        h1[0]=(__bf16)f2.x; h1[1]=(__bf16)f2.y; h1[2]=(__bf16)f2.z; h1[3]=(__bf16)f2.w;
        h1[4]=(__bf16)f3.x; h1[5]=(__bf16)f3.y; h1[6]=(__bf16)f3.z; h1[7]=(__bf16)f3.w;
        ((bf16x8*)op)[t*2]   = h0;
        ((bf16x8*)op)[t*2+1] = h1;
        if (isv) {
            // beta partials for the 3 layers (same visit row)
            #pragma unroll
            for (int l = 0; l < LL; l++) {
                const float4* bw = (const float4*)(beta_w + (long)l*4000) + t*4;
                float4 b0 = bw[0], b1 = bw[1], b2 = bw[2], b3 = bw[3];
                float s = f0.x*b0.x + f0.y*b0.y + f0.z*b0.z + f0.w*b0.w
                        + f1.x*b1.x + f1.y*b1.y + f1.z*b1.z + f1.w*b1.w
                        + f2.x*b2.x + f2.y*b2.y + f2.z*b2.z + f2.w*b2.w
                        + f3.x*b3.x + f3.y*b3.y + f3.z*b3.z + f3.w*b3.w;
                if (l == 0) p0 = s; else if (l == 1) p1 = s; else p2 = s;
            }
        }
    } else if (t < 254) {
        bf16x8 zz;
        #pragma unroll
        for (int j = 0; j < 8; j++) zz[j] = (__bf16)0.f;
        ((bf16x8*)op)[500 + (t - 250)] = zz;
    }
    if (isv) {
        __shared__ float r0[256], r1[256], r2[256];
        r0[t] = p0; r1[t] = p1; r2[t] = p2;
        __syncthreads();
        for (int o = 128; o > 0; o >>= 1) {
            if (t < o) { r0[t] += r0[t+o]; r1[t] += r1[t+o]; r2[t] += r2[t+o]; }
            __syncthreads();
        }
        if (t == 0) {
            int v = (int)(bid % VV);
            float lam = __expf(DECAYF * (float)(VV - v));
            betab[0*BV*VV + bid] = tanhf(r0[0] + beta_b[0]) * lam;
            betab[1*BV*VV + bid] = tanhf(r1[0] + beta_b[1]) * lam;
            betab[2*BV*VV + bid] = tanhf(r2[0] + beta_b[2]) * lam;
        }
    }
}

// ---------------- alpha GEMM: z[l,row,col] = visit[row,:] . alpha_w[l][col,:] ----------------
// bf16 in (stride AK), BK=64 glds16 staging, XOR-swizzled LDS (0 bank conflicts, R5),
// XCD-grouped swizzle (R3), split-K=4 with bf16 partial stores (R6).
__global__ __launch_bounds__(256)
void gemm_alpha(const __bf16* __restrict__ visit_bf, const __bf16* __restrict__ alpha_bf,
                __bf16* __restrict__ zpart)
{
    __shared__ __bf16 Ah[128*64];   // granule g of row r at r*64 + (g^(r&7))*8
    __shared__ __bf16 Bh[128*64];

    const int id   = blockIdx.x;      // 0..1919
    const int xcd  = id & 7;
    const int slot = id >> 3;         // 0..239
    const int mi   = slot % 5;        // 0..4
    const int gix  = slot / 5;        // 0..47
    const int g    = xcd * 48 + gix;  // 0..383
    const int ni   = g & 31;          // 0..31
    const int lkh  = g >> 5;          // 0..11
    const int l    = lkh >> 2;        // 0..2
    const int kh   = lkh & 3;         // 0..3

    const __bf16* Ag = visit_bf;
    const __bf16* Bg = alpha_bf + (long)l * NNODES * AK;
    __bf16*       Cg = zpart + (long)kh * ZSTRIDE + (long)l * 640 * 4000;
    const int m0 = mi * 128;
    const int n0 = ni * 128;
    const int k0 = kh * 1024;
    const int k1 = (kh == 3) ? AK : (k0 + 1024);

    const int tid = threadIdx.x;
    const int wv  = tid >> 6;
    const int ln  = tid & 63;
    const int srow = ln >> 3;
    const int gsl  = (ln & 7) ^ srow;

    const __bf16* aA = Ag + (long)(m0 + wv*8 + srow) * AK + gsl*8;
    const __bf16* bB[4];
    #pragma unroll
    for (int t = 0; t < 4; t++) {
        int br = n0 + wv*8 + srow + t*32;
        if (br > NNODES-1) br = NNODES-1;      // clamp (cols>=4000 masked at store)
        bB[t] = Bg + (long)br * AK + gsl*8;
    }

    const int wm = (wv & 1) * 64;
    const int wn = (wv >> 1) * 64;
    const int lr = ln & 15;
    const int kq = ln >> 4;
    const int sw0 = lr & 7;

    f32x4 acc[4][4];
    #pragma unroll
    for (int i = 0; i < 4; i++)
        #pragma unroll
        for (int j = 0; j < 4; j++)
            acc[i][j] = (f32x4){0.f, 0.f, 0.f, 0.f};

    for (int kb = k0; kb < k1; kb += 64) {
        #pragma unroll
        for (int t = 0; t < 4; t++) {
            glds16(aA + (long)t*32*AK + kb, &Ah[(t*4 + wv) * 512]);
            glds16(bB[t] + kb,              &Bh[(t*4 + wv) * 512]);
        }
        __syncthreads();
        #pragma unroll
        for (int ks = 0; ks < 2; ks++) {
            const int sg = ((ks*4 + kq) ^ sw0) * 8;
            bf16x8 af[4], bfr[4];
            #pragma unroll
            for (int i = 0; i < 4; i++) {
                af[i]  = *(const bf16x8*)&Ah[(wm + i*16 + lr)*64 + sg];
                bfr[i] = *(const bf16x8*)&Bh[(wn + i*16 + lr)*64 + sg];
            }
            #pragma unroll
            for (int i = 0; i < 4; i++)
                #pragma unroll
                for (int j = 0; j < 4; j++)
                    acc[i][j] = __builtin_amdgcn_mfma_f32_16x16x32_bf16(af[i], bfr[j], acc[i][j], 0, 0, 0);
        }
        __syncthreads();
    }

    // C/D layout col=lane&15, row=(lane>>4)*4+reg (m89/m91-verified)
    #pragma unroll
    for (int i = 0; i < 4; i++) {
        const int row_b = m0 + wm + i*16 + kq*4;   // < 640 always
        #pragma unroll
        for (int j = 0; j < 4; j++) {
            const int col = n0 + wn + j*16 + lr;
            if (col < NNODES) {
                #pragma unroll
                for (int r = 0; r < 4; r++)
                    Cg[(long)(row_b + r)*4000 + col] = (__bf16)acc[i][j][r];
            }
        }
    }
}

// ---------------- generic small GEMM (C = A * B^T), split-bf16 for ~f32 accuracy ----------------
#define BM 128
#define BN 128
#define BKG 32
#define LSTR 40

template<int SPLIT>
__device__ __forceinline__ void stage_tile(const float* __restrict__ G, int rows, int Kdim,
                                           int r0, int kb, int k1, __bf16* Sh, __bf16* Sl, int tid)
{
    const int sr  = tid >> 1;
    const int skc = (tid & 1) * 16;
    const int gr  = r0 + sr;
    const int gk  = kb + skc;
    float va[16];
    if (gr < rows && gk + 16 <= k1) {
        const float4* p4 = (const float4*)(G + (long)gr * Kdim + gk);
        #pragma unroll
        for (int q = 0; q < 4; q++) {
            float4 f = p4[q];
            va[4*q+0] = f.x; va[4*q+1] = f.y; va[4*q+2] = f.z; va[4*q+3] = f.w;
        }
    } else {
        #pragma unroll
        for (int j = 0; j < 16; j++) {
            int kk = gk + j;
            va[j] = (gr < rows && kk < k1) ? G[(long)gr * Kdim + kk] : 0.0f;
        }
    }
    bf16x8 h[2], lo[2];
    #pragma unroll
    for (int half = 0; half < 2; half++) {
        #pragma unroll
        for (int j = 0; j < 8; j++) {
            float v = va[half*8 + j];
            __bf16 hi = (__bf16)v;
            h[half][j]  = hi;
            lo[half][j] = (__bf16)(v - (float)hi);
        }
    }
    *(bf16x8*)&Sh[sr*LSTR + skc]     = h[0];
    *(bf16x8*)&Sh[sr*LSTR + skc + 8] = h[1];
    if (SPLIT) {
        *(bf16x8*)&Sl[sr*LSTR + skc]     = lo[0];
        *(bf16x8*)&Sl[sr*LSTR + skc + 8] = lo[1];
    }
}

template<int SPLIT, int RELU, int BIAS, int WRITEB>
__global__ __launch_bounds__(256)
void gemm_bt(const float* __restrict__ Ag, const float* __restrict__ Bg,
             float* __restrict__ Cg, const float* __restrict__ bias,
             __bf16* __restrict__ Xb, int M, int N, int K)
{
    __shared__ __bf16 Ah[BM*LSTR];
    __shared__ __bf16 Bh[BN*LSTR];
    __shared__ __bf16 Alo[SPLIT ? BM*LSTR : 1];
    __shared__ __bf16 Blo[SPLIT ? BN*LSTR : 1];

    const int tid = threadIdx.x;
    const int m0 = blockIdx.x * BM;
    const int n0 = blockIdx.y * BN;

    const int wave = tid >> 6;
    const int lane = tid & 63;
    const int wm = (wave & 1) * 64;
    const int wn = (wave >> 1) * 64;
    const int lr = lane & 15;
    const int kq = lane >> 4;

    f32x4 acc[4][4];
    #pragma unroll
    for (int i = 0; i < 4; i++)
        #pragma unroll
        for (int j = 0; j < 4; j++)
            acc[i][j] = (f32x4){0.f, 0.f, 0.f, 0.f};

    for (int kb = 0; kb < K; kb += BKG) {
        stage_tile<SPLIT>(Ag, M, K, m0, kb, K, Ah, Alo, tid);
        stage_tile<SPLIT>(Bg, N, K, n0, kb, K, Bh, Blo, tid);
        __syncthreads();

        bf16x8 af[4], bfr[4];
        #pragma unroll
        for (int i = 0; i < 4; i++) {
            af[i]  = *(const bf16x8*)&Ah[(wm + i*16 + lr)*LSTR + kq*8];
            bfr[i] = *(const bf16x8*)&Bh[(wn + i*16 + lr)*LSTR + kq*8];
        }
        #pragma unroll
        for (int i = 0; i < 4; i++)
            #pragma unroll
            for (int j = 0; j < 4; j++)
                acc[i][j] = __builtin_amdgcn_mfma_f32_16x16x32_bf16(af[i], bfr[j], acc[i][j], 0, 0, 0);

        if (SPLIT) {
            bf16x8 al[4], bl[4];
            #pragma unroll
            for (int i = 0; i < 4; i++) {
                al[i] = *(const bf16x8*)&Alo[(wm + i*16 + lr)*LSTR + kq*8];
                bl[i] = *(const bf16x8*)&Blo[(wn + i*16 + lr)*LSTR + kq*8];
            }
            #pragma unroll
            for (int i = 0; i < 4; i++)
                #pragma unroll
                for (int j = 0; j < 4; j++) {
                    acc[i][j] = __builtin_amdgcn_mfma_f32_16x16x32_bf16(af[i], bl[j], acc[i][j], 0, 0, 0);
                    acc[i][j] = __builtin_amdgcn_mfma_f32_16x16x32_bf16(al[i], bfr[j], acc[i][j], 0, 0, 0);
                }
        }
        __syncthreads();
    }

    #pragma unroll
    for (int i = 0; i < 4; i++) {
        const int row_b = m0 + wm + i*16 + kq*4;
        #pragma unroll
        for (int j = 0; j < 4; j++) {
            const int col = n0 + wn + j*16 + lr;
            if (col < N) {
                #pragma unroll
                for (int r = 0; r < 4; r++) {
                    const int row = row_b + r;
                    if (row < M) {
                        float v = acc[i][j][r];
                        if (BIAS) v += bias[col];
                        if (RELU) v = fmaxf(v, 0.0f);
                        Cg[(long)row*N + col] = v;
                        if (WRITEB) Xb[(long)row*N + col] = (__bf16)v;
                    }
                }
            }
        }
    }
}

// ---------------- CSR build (count fused into k_cvt2: R9) ----------------
// per-block sum of 256 degrees -> bsum[block]
__global__ __launch_bounds__(256) void k_scan1(const int* __restrict__ deg, int* __restrict__ bsum) {
    __shared__ int red[256];
    int t = threadIdx.x;
    int i = blockIdx.x*256 + t;
    red[t] = (i < WS_N) ? deg[i] : 0;
    __syncthreads();
    for (int o = 128; o > 0; o >>= 1) {
        if (t < o) red[t] += red[t + o];
        __syncthreads();
    }
    if (t == 0) bsum[blockIdx.x] = red[0];
}

// fused: every block redundantly scans the 196 block sums (cheap), then local scan -> offs, cursor
__global__ __launch_bounds__(256) void k_scan3(const int* __restrict__ deg, const int* __restrict__ bsum,
                                               int* __restrict__ offs, int* __restrict__ cursor) {
    __shared__ int sb[256];
    __shared__ int s[256];
    int t = threadIdx.x;
    int bv = (t < SCAN_NB) ? bsum[t] : 0;
    sb[t] = bv;
    __syncthreads();
    for (int o = 1; o < 256; o <<= 1) {
        int add = (t >= o) ? sb[t - o] : 0;
        __syncthreads();
        sb[t] += add;
        __syncthreads();
    }
    int base = (blockIdx.x == 0) ? 0 : sb[blockIdx.x - 1];   // exclusive block base

    int i = blockIdx.x*256 + t;
    int v = (i < WS_N) ? deg[i] : 0;
    s[t] = v;
    __syncthreads();
    for (int o = 1; o < 256; o <<= 1) {
        int add = (t >= o) ? s[t - o] : 0;
        __syncthreads();
        s[t] += add;
        __syncthreads();
    }
    if (i < WS_N) {
        int e = base + s[t] - v;
        offs[i] = e;
        cursor[i] = e;
    }
    if (blockIdx.x == 0 && t == 0) offs[WS_N] = WS_E;
}

// R9: pack (src,rel) into one uint32 (src<2^16, rel<2^8) -> halves scatter + gather traffic
__global__ void k_fill(const int* __restrict__ dst, const int* __restrict__ src,
                       const int* __restrict__ rel, int* __restrict__ cursor,
                       uint32_t* __restrict__ sr) {
    int e = blockIdx.x*256 + threadIdx.x;
    if (e < WS_E) {
        int d = dst[e];
        int p = atomicAdd(&cursor[d], 1);
        sr[p] = (uint32_t)src[e] | ((uint32_t)rel[e] << 16);
    }
}

// ---------------- small precompute kernels ----------------
// fused Wrel GEMM + relmsg: exact f32
__global__ __launch_bounds__(128) void k_relfused(const float* __restrict__ rel_emb,
                                                  const float* __restrict__ lin_w,
                                                  const float* __restrict__ lin_b,
                                                  const float* __restrict__ wr_w,
                                                  const float* __restrict__ wr_b,
                                                  __bf16* __restrict__ relmsg) {
    int r = blockIdx.x;    // 0..NRELS-1
    int o = threadIdx.x;   // 0..127
    __shared__ float row[128];
    __shared__ float red[128];
    row[o] = rel_emb[(long)r*EMB + o];
    __syncthreads();
    float wv = lin_b[o];
    #pragma unroll 4
    for (int k = 0; k < EMB; k++) wv += row[k] * lin_w[(long)o*EMB + k];
    #pragma unroll
    for (int l = 0; l < LL; l++) {
        red[o] = wv * wr_w[l*HIDD + o];
        __syncthreads();
        for (int s2 = 64; s2 > 0; s2 >>= 1) {
            if (o < s2) red[o] += red[o + s2];
            __syncthreads();
        }
        float wrel = red[0] + wr_b[l];
        __syncthreads();   // all lanes read red[0] before next-l overwrite
        relmsg[((long)l*NRELS + r)*HIDD + o] = (__bf16)(wrel * wv);
    }
}

// x init + bf16 shadow + per-layer node attention gather (fused)
__global__ void k_xinit(const float* __restrict__ Wnode, const int* __restrict__ nid,
                        const int* __restrict__ batch, const float* __restrict__ attn,
                        float* __restrict__ x, __bf16* __restrict__ xb, float* __restrict__ an) {
    int t = blockIdx.x*256 + threadIdx.x;
    if (t >= WS_N*32) return;
    int i = t >> 5;
    int d = t & 31;
    int n = nid[i];
    float4 v = ((const float4*)Wnode)[n*32 + d];
    ((float4*)x)[i*32 + d] = v;
    bf16x4 b;
    b[0] = (__bf16)v.x; b[1] = (__bf16)v.y; b[2] = (__bf16)v.z; b[3] = (__bf16)v.w;
    ((bf16x4*)xb)[i*32 + d] = b;
    if (d < LL) an[(long)d*WS_N + i] = attn[((long)d*BV + batch[i]) * NNODES + n];
}

// softmax over v + beta-weighted pool; sums the 4 bf16 split-K partials inline
__global__ __launch_bounds__(256) void k_attnpool(const __bf16* __restrict__ zpart,
                                                  const float* __restrict__ beta, float* __restrict__ attn) {
    int m = blockIdx.x*256 + threadIdx.x;
    int b = blockIdx.y;
    int l = blockIdx.z;
    if (m >= NNODES) return;
    const __bf16* zp = zpart + ((long)l*640 + b*VV) * 4000 + m;
    const float* bet = beta + (l*BV + b) * VV;
    float zv[VV];
    float mx = -1e30f;
    #pragma unroll
    for (int v = 0; v < VV; v++) {
        long o = (long)v * 4000;
        float s = (float)zp[o] + (float)zp[ZSTRIDE + o] + (float)zp[2*ZSTRIDE + o] + (float)zp[3*ZSTRIDE + o];
        zv[v] = s;
        mx = fmaxf(mx, s);
    }
    float s = 0.f, ws = 0.f;
    #pragma unroll
    for (int v = 0; v < VV; v++) {
        float e = __expf(zv[v] - mx);
        s += e;
        ws += e * bet[v];
    }
    attn[((long)l*BV + b) * NNODES + m] = ws / s;
}

// ---------------- message + aggregate ----------------
// R9: 16 lanes per edge, bf16x8 = 16B/lane gathers (G13 sweet spot). Per 8 edges:
// 8 VMEM instrs (2 sr + 2 an + 2 xb + 2 relmsg) vs 16 in R8. Cross-edge combine
// (shfl_xor 16/32) moved entirely out of the loop.
__global__ __launch_bounds__(256) void k_agg(const float* __restrict__ x, const __bf16* __restrict__ xb,
                                             const float* __restrict__ an,
                                             const __bf16* __restrict__ relmsg_l, const int* __restrict__ offs,
                                             const uint32_t* __restrict__ sr,
                                             float* __restrict__ outb) {
    int node = blockIdx.x*4 + (threadIdx.x >> 6);   // grid exact: 12500*4 = WS_N
    int lane = threadIdx.x & 63;
    int eh = lane >> 4;     // edge slot within quad (0..3)
    int lh = lane & 15;     // dim octet: dims [lh*8, lh*8+8)
    int e0 = offs[node], e1 = offs[node + 1];
    const bf16x8* xb8 = (const bf16x8*)xb;
    const bf16x8* rm8 = (const bf16x8*)relmsg_l;
    float acc[8];
    #pragma unroll
    for (int d = 0; d < 8; d++) acc[d] = 0.f;
    int e = e0;
    for (; e + 8 <= e1; e += 8) {
        uint32_t p0 = sr[e + eh], p1 = sr[e + 4 + eh];
        int s0 = p0 & 0xFFFF, r0 = p0 >> 16;
        int s1 = p1 & 0xFFFF, r1 = p1 >> 16;
        float a0 = an[s0], a1 = an[s1];
        bf16x8 g0 = xb8[s0*16 + lh], g1 = xb8[s1*16 + lh];
        bf16x8 m0 = rm8[r0*16 + lh], m1 = rm8[r1*16 + lh];
        #pragma unroll
        for (int d = 0; d < 8; d++) {
            acc[d] += fmaxf((float)g0[d]*a0 + (float)m0[d], 0.f);
            acc[d] += fmaxf((float)g1[d]*a1 + (float)m1[d], 0.f);
        }
    }
    for (; e + 4 <= e1; e += 4) {
        uint32_t p = sr[e + eh];
        int s = p & 0xFFFF, r = p >> 16;
        float a = an[s];
        bf16x8 g = xb8[s*16 + lh];
        bf16x8 m = rm8[r*16 + lh];
        #pragma unroll
        for (int d = 0; d < 8; d++)
            acc[d] += fmaxf((float)g[d]*a + (float)m[d], 0.f);
    }
    if (e + eh < e1) {
        uint32_t p = sr[e + eh];
        int s = p & 0xFFFF, r = p >> 16;
        float a = an[s];
        bf16x8 g = xb8[s*16 + lh];
        bf16x8 m = rm8[r*16 + lh];
        #pragma unroll
        for (int d = 0; d < 8; d++)
            acc[d] += fmaxf((float)g[d]*a + (float)m[d], 0.f);
    }
    // combine the 4 edge slots: lanes with equal lh hold the same dims
    #pragma unroll
    for (int d = 0; d < 8; d++) {
        acc[d] += __shfl_xor(acc[d], 16);
        acc[d] += __shfl_xor(acc[d], 32);
    }
    if (eh == 0) {
        float4 x0 = ((const float4*)x)[node*32 + lh*2];
        float4 x1 = ((const float4*)x)[node*32 + lh*2 + 1];
        float4 o0, o1;
        o0.x = acc[0] + x0.x; o0.y = acc[1] + x0.y; o0.z = acc[2] + x0.z; o0.w = acc[3] + x0.w;
        o1.x = acc[4] + x1.x; o1.y = acc[5] + x1.y; o1.z = acc[6] + x1.z; o1.w = acc[7] + x1.w;
        ((float4*)outb)[node*32 + lh*2]     = o0;
        ((float4*)outb)[node*32 + lh*2 + 1] = o1;
    }
}

// ---------------- pooling partials (graph-mean + ehr branch fused) ----------------
__global__ __launch_bounds__(256) void k_pool(const float* __restrict__ x,
                                              const int* __restrict__ batch,
                                              const float* __restrict__ ehr,
                                              const float* __restrict__ node_emb,
                                              float* __restrict__ xgsum,
                                              float* __restrict__ xnsum,
                                              float* __restrict__ esum) {
    if (blockIdx.x < NPP) {
        // graph-sum partials
        int r0 = blockIdx.x * 128;
        int d = threadIdx.x & 127;
        int rofs = threadIdx.x >> 7;
        int r1 = min(r0 + 128, WS_N);
        float acc = 0.f;
        int curb = -1;
        for (int i = r0 + rofs; i < r1; i += 2) {
            int b = batch[i];
            if (b != curb) {
                if (curb >= 0) atomicAdd(&xgsum[curb*HIDD + d], acc);
                acc = 0.f; curb = b;
            }
            acc += x[(long)i*HIDD + d];
        }
        if (curb >= 0) atomicAdd(&xgsum[curb*HIDD + d], acc);
    } else {
        // ehr pooling
        int id = blockIdx.x - NPP;     // 0..511
        int b = id >> 4;
        int c = id & 15;
        int d = threadIdx.x;
        int n0 = c * (NNODES/16), n1 = n0 + (NNODES/16);
        __shared__ float red[256];
        if (d < 128) {
            float acc = 0.f;
            for (int n = n0; n < n1; n++)
                acc += ehr[b*NNODES + n] * node_emb[(long)n*HIDD + d];
            atomicAdd(&xnsum[b*HIDD + d], acc);
        }
        float s = 0.f;
        for (int n = n0 + d; n < n1; n += 256) s += ehr[b*NNODES + n];
        red[d] = s; __syncthreads();
        for (int o = 128; o > 0; o >>= 1) {
            if (d < o) red[d] += red[d + o];
            __syncthreads();
        }
        if (d == 0) atomicAdd(&esum[b], red[0]);
    }
}

// fused head: batch-count (binary search) + mean + x_node linear + concat + mlp
__global__ __launch_bounds__(128) void k_head(const float* __restrict__ xgsum,
                                              const float* __restrict__ xnsum,
                                              const float* __restrict__ esum,
                                              const int* __restrict__ batch,
                                              const float* __restrict__ lin_w, const float* __restrict__ lin_b,
                                              const float* __restrict__ mlp_w, const float* __restrict__ mlp_b,
                                              float* __restrict__ out) {
    int b = blockIdx.x;
    int d = threadIdx.x;
    int lo = 0, hi = WS_N;
    while (lo < hi) { int mid = (lo + hi) >> 1; if (batch[mid] < b) lo = mid + 1; else hi = mid; }
    int s0 = lo;
    lo = 0; hi = WS_N;
    while (lo < hi) { int mid = (lo + hi) >> 1; if (batch[mid] < b + 1) lo = mid + 1; else hi = mid; }
    int cnt = max(lo - s0, 1);
    __shared__ float t1[128];
    __shared__ float cat[2*HIDD];
    t1[d]  = xnsum[b*HIDD + d] / esum[b];
    cat[d] = xgsum[b*HIDD + d] / (float)cnt;
    __syncthreads();
    float o2 = lin_b[d];
    for (int k2 = 0; k2 < HIDD; k2++) o2 += t1[k2] * lin_w[d*HIDD + k2];
    cat[HIDD + d] = o2;
    __syncthreads();
    if (d < OUTD) {
        float a = mlp_b[d];
        for (int j = 0; j < 2*HIDD; j++) a += cat[j] * mlp_w[d*2*HIDD + j];
        out[b*OUTD + d] = a;
    }
}

// ---------------- launcher ----------------
extern "C" void kernel_launch(void* const* d_in, const int* in_sizes, int n_in,
                              void* d_out, int out_size, void* d_ws, size_t ws_size,
                              hipStream_t stream)
{
    const float* node_emb = (const float*)d_in[0];
    const float* rel_emb  = (const float*)d_in[1];
    const float* lin_w    = (const float*)d_in[2];
    const float* lin_b    = (const float*)d_in[3];
    const float* alpha_w  = (const float*)d_in[4];
    // d_in[5] alpha_b: shift-invariant under softmax over v -> unused
    const float* beta_w   = (const float*)d_in[6];
    const float* beta_b   = (const float*)d_in[7];
    const float* wr_w     = (const float*)d_in[8];
    const float* wr_b     = (const float*)d_in[9];
    const float* conv_w   = (const float*)d_in[10];
    const float* conv_b   = (const float*)d_in[11];
    const float* mlp_w    = (const float*)d_in[12];
    const float* mlp_b    = (const float*)d_in[13];
    const float* visit    = (const float*)d_in[14];
    const float* ehr      = (const float*)d_in[15];
    const int* node_ids   = (const int*)d_in[16];
    const int* rel_ids    = (const int*)d_in[17];
    const int* ei         = (const int*)d_in[18];
    const int* batch      = (const int*)d_in[19];
    const int* esrc = ei;
    const int* edst = ei + WS_E;
    float* out = (float*)d_out;

    char* p = (char*)d_ws;
    auto take = [&](size_t bytes) -> char* {
        char* q = p;
        p += (bytes + 255) & ~(size_t)255;
        return q;
    };
    __bf16* zpart    = (__bf16*)take((size_t)4*ZSTRIDE*2);        // 61.4 MB: 4 bf16 split-K partials (aggbuf later)
    __bf16* visit_bf = (__bf16*)take((size_t)(BV*VV)*AK*2);       // 5.2 MB
    char*   big      = take((size_t)LL*NNODES*AK*2);              // 96.8 MB: alpha_bf, then carved
    float* betab  = (float*)take((size_t)LL*BV*VV*4);
    // zeroed region: xgsum..deg contiguous -> single memset
    float* xgsum  = (float*)take((size_t)BV*HIDD*4);
    float* xnsum  = (float*)take((size_t)BV*HIDD*4);
    float* esum   = (float*)take((size_t)BV*4);
    int* deg      = (int*)take((size_t)WS_N*4);
    size_t zero_bytes = (size_t)((char*)(deg + WS_N) - (char*)xgsum);
    int* offs     = (int*)take((size_t)(WS_N+1)*4);
    int* cursor   = (int*)take((size_t)WS_N*4);
    int* bsum     = (int*)take((size_t)SCAN_NB*4);
    if ((size_t)(p - (char*)d_ws) > ws_size) return;  // ws too small: leave output poisoned (visible failure)

    // alpha_bf occupies `big` during cvt+gemm_alpha; afterwards carved (stream-ordered -> safe):
    __bf16* alpha_bf = (__bf16*)big;
    char* q = big;
    auto carve = [&](size_t bytes) -> char* {
        char* r = q;
        q += (bytes + 255) & ~(size_t)255;
        return r;
    };
    float*    x      = (float*)carve((size_t)WS_N*HIDD*4);     // 25.6 MB
    __bf16*   xb     = (__bf16*)carve((size_t)WS_N*HIDD*2);    // 12.8 MB
    uint32_t* sr     = (uint32_t*)carve((size_t)WS_E*4);       // 3.2 MB (packed: R9)
    float*    attn   = (float*)carve((size_t)LL*BV*NNODES*4);  // 1.5 MB (written by attnpool AFTER gemm_alpha)
    float*    attnnd = (float*)carve((size_t)LL*WS_N*4);       // 0.6 MB
    float*    Wnode  = (float*)carve((size_t)NNODES*HIDD*4);   // 2.0 MB
    __bf16*   relmsg = (__bf16*)carve((size_t)LL*NRELS*HIDD*2);
    float*    aggbuf = (float*)zpart;                          // zpart dead after attnpool

    (void)hipMemsetAsync(xgsum, 0, zero_bytes, stream);

    // ---- phase 1: alpha attention (beta + edge-count fused into cvt2) ----
    k_cvt2<<<dim3(CVT_NB + CNT_NB), 256, 0, stream>>>(visit, alpha_w, beta_w, beta_b,
                                                      visit_bf, alpha_bf, betab, edst, deg);
    gemm_alpha<<<dim3(1920), 256, 0, stream>>>(visit_bf, alpha_bf, zpart);
    k_attnpool<<<dim3((NNODES+255)/256, BV, LL), 256, 0, stream>>>(zpart, betab, attn);

    // ---- phase 2: graph features (carved from the now-dead alpha_bf region) ----
    k_scan1<<<dim3(SCAN_NB), 256, 0, stream>>>(deg, bsum);
    k_scan3<<<dim3(SCAN_NB), 256, 0, stream>>>(deg, bsum, offs, cursor);
    k_fill<<<dim3((WS_E+255)/256), 256, 0, stream>>>(edst, esrc, rel_ids, cursor, sr);

    gemm_bt<1,0,1,0><<<dim3((NNODES+BM-1)/BM, 1, 1), 256, 0, stream>>>(
        node_emb, lin_w, Wnode, lin_b, nullptr, NNODES, HIDD, HIDD);
    k_relfused<<<dim3(NRELS), 128, 0, stream>>>(rel_emb, lin_w, lin_b, wr_w, wr_b, relmsg);
    k_xinit<<<dim3((WS_N*32+255)/256), 256, 0, stream>>>(Wnode, node_ids, batch, attn, x, xb, attnnd);

    // ---- phase 3: GNN layers (last layer skips xb: dead afterwards) ----
    for (int l = 0; l < LL; l++) {
        k_agg<<<dim3(WS_N/4), 256, 0, stream>>>(
            x, xb, attnnd + (size_t)l*WS_N, relmsg + (size_t)l*NRELS*HIDD, offs, sr, aggbuf);
        if (l < LL-1)
            gemm_bt<1,1,1,1><<<dim3((WS_N+BM-1)/BM, 1, 1), 256, 0, stream>>>(
                aggbuf, conv_w + (size_t)l*HIDD*HIDD, x, conv_b + (size_t)l*HIDD, xb,
                WS_N, HIDD, HIDD);
        else
            gemm_bt<1,1,1,0><<<dim3((WS_N+BM-1)/BM, 1, 1), 256, 0, stream>>>(
                aggbuf, conv_w + (size_t)l*HIDD*HIDD, x, conv_b + (size_t)l*HIDD, nullptr,
                WS_N, HIDD, HIDD);
    }

    // ---- phase 4: pooling + head ----
    k_pool<<<dim3(NPP + 16*BV), 256, 0, stream>>>(x, batch, ehr, node_emb, xgsum, xnsum, esum);
    k_head<<<BV, 128, 0, stream>>>(xgsum, xnsum, esum, batch, lin_w, lin_b, mlp_w, mlp_b, out);
}